// Round 17
// baseline (2259.213 us; speedup 1.0000x reference)
//
#include <hip/hip_runtime.h>
#include <math.h>

#define SEQ    128
#define BATCH  32
#define NINP   1024
#define NGATE  4096   // 4*NINP
#define DEPTH  10
#define NPOL   22     // 2*(DEPTH+1)
#define NVOCAB 32000
#define DEC_OFF 131072000ll   // SEQ*BATCH*NVOCAB
#define NGB    64             // gate blocks
#define NMB    32             // mem blocks
#define NDB    160            // decode blocks
#define XG_OFF 114294784      // DEC_OFF - 16777216: xg in the TAIL of decoded (rows 3572+)

typedef __attribute__((ext_vector_type(8))) short bf16x8;
typedef __attribute__((ext_vector_type(4))) float f32x4;

__device__ __forceinline__ float sigf(float x){ return 1.0f/(1.0f + expf(-x)); }

__device__ __forceinline__ unsigned short f2bf(float x){
  unsigned int u = __float_as_uint(x);
  unsigned int r = (u + 0x7FFFu + ((u >> 16) & 1u)) >> 16;   // RNE
  return (unsigned short)r;
}
__device__ __forceinline__ float bf2f(unsigned short u){
  return __uint_as_float(((unsigned int)u) << 16);
}

// ---------------- init: h0 -> packed bf16 pairs into hsx slot 0 ----------------
__global__ __launch_bounds__(256) void k_init(const float* __restrict__ h0,
    unsigned int* __restrict__ hsx0){
  int i = blockIdx.x*256 + threadIdx.x;   // < 16384
  unsigned int u = (unsigned int)f2bf(h0[2*i]) | ((unsigned int)f2bf(h0[2*i+1]) << 16);
  hsx0[i] = u;                            // layout: b*512 + n/2
}

// ---------------- w_hh -> bf16, swizzled to per-wave MFMA fragment layout ----------------
__global__ __launch_bounds__(256) void k_wconv(const float* __restrict__ w_hh,
    unsigned short* __restrict__ w_swz){
  int id = blockIdx.x*256 + threadIdx.x;          // 0..524287
  int lane = id & 63, kc = (id>>6)&7, kq = (id>>9)&3, nt = id>>11;
  int j = nt*16 + (lane&15);
  int k = kq*256 + kc*32 + (lane>>4)*8;
  const float* src = w_hh + (size_t)j*NINP + k;
  bf16x8 d;
  #pragma unroll
  for (int e=0;e<8;e++) d[e] = (short)f2bf(src[e]);
  *(bf16x8*)(w_swz + (size_t)id*8) = d;
}

// ---------------- bf16 MFMA GEMM (f32 sources, reg-staged): C = A.B^T + bias ----------------
__global__ __launch_bounds__(256) void k_gemm_bf16(
    const float* __restrict__ A, const int* __restrict__ Aidx,
    const float* __restrict__ B, const float* __restrict__ bias0,
    const float* __restrict__ bias1, float* __restrict__ C,
    int K, int ldc){
  __shared__ __align__(16) unsigned short As[128][40];
  __shared__ __align__(16) unsigned short Bs[128][40];
  const int m1 = blockIdx.y*128, n1 = blockIdx.x*128;
  const int tid = threadIdx.x;
  const int wave = tid >> 6, lane = tid & 63;
  const int wr = (wave >> 1) * 64, wc = (wave & 1) * 64;
  const int fr = lane & 15, fq = lane >> 4;

  f32x4 acc[4][4];
  #pragma unroll
  for (int i=0;i<4;i++)
    #pragma unroll
    for (int j=0;j<4;j++) acc[i][j] = (f32x4){0.f,0.f,0.f,0.f};

  const int sr = tid >> 1, sk = (tid & 1) * 16;
  const float* arow = Aidx ? (A + (size_t)Aidx[m1+sr]*K) : (A + (size_t)(m1+sr)*K);
  const float* brow = B + (size_t)(n1+sr)*K;

  for (int k0 = 0; k0 < K; k0 += 32){
    float4 a0 = *(const float4*)(arow + k0 + sk);
    float4 a1 = *(const float4*)(arow + k0 + sk + 4);
    float4 a2 = *(const float4*)(arow + k0 + sk + 8);
    float4 a3 = *(const float4*)(arow + k0 + sk + 12);
    float4 b0 = *(const float4*)(brow + k0 + sk);
    float4 b1 = *(const float4*)(brow + k0 + sk + 4);
    float4 b2 = *(const float4*)(brow + k0 + sk + 8);
    float4 b3 = *(const float4*)(brow + k0 + sk + 12);
    bf16x8 ap0, ap1, bp0, bp1;
    ap0[0]=f2bf(a0.x); ap0[1]=f2bf(a0.y); ap0[2]=f2bf(a0.z); ap0[3]=f2bf(a0.w);
    ap0[4]=f2bf(a1.x); ap0[5]=f2bf(a1.y); ap0[6]=f2bf(a1.z); ap0[7]=f2bf(a1.w);
    ap1[0]=f2bf(a2.x); ap1[1]=f2bf(a2.y); ap1[2]=f2bf(a2.z); ap1[3]=f2bf(a2.w);
    ap1[4]=f2bf(a3.x); ap1[5]=f2bf(a3.y); ap1[6]=f2bf(a3.z); ap1[7]=f2bf(a3.w);
    bp0[0]=f2bf(b0.x); bp0[1]=f2bf(b0.y); bp0[2]=f2bf(b0.z); bp0[3]=f2bf(b0.w);
    bp0[4]=f2bf(b1.x); bp0[5]=f2bf(b1.y); bp0[6]=f2bf(b1.z); bp0[7]=f2bf(b1.w);
    bp1[0]=f2bf(b2.x); bp1[1]=f2bf(b2.y); bp1[2]=f2bf(b2.z); bp1[3]=f2bf(b2.w);
    bp1[4]=f2bf(b3.x); bp1[5]=f2bf(b3.y); bp1[6]=f2bf(b3.z); bp1[7]=f2bf(b3.w);

    __syncthreads();
    *(bf16x8*)&As[sr][sk]     = ap0;
    *(bf16x8*)&As[sr][sk + 8] = ap1;
    *(bf16x8*)&Bs[sr][sk]     = bp0;
    *(bf16x8*)&Bs[sr][sk + 8] = bp1;
    __syncthreads();

    bf16x8 af[4], bf[4];
    #pragma unroll
    for (int mi=0; mi<4; mi++) af[mi] = *(const bf16x8*)&As[wr + mi*16 + fr][fq*8];
    #pragma unroll
    for (int ni=0; ni<4; ni++) bf[ni] = *(const bf16x8*)&Bs[wc + ni*16 + fr][fq*8];
    #pragma unroll
    for (int mi=0; mi<4; mi++)
      #pragma unroll
      for (int ni=0; ni<4; ni++)
        acc[mi][ni] = __builtin_amdgcn_mfma_f32_16x16x32_bf16(af[mi], bf[ni], acc[mi][ni], 0, 0, 0);
  }

  #pragma unroll
  for (int ni=0; ni<4; ni++){
    const int col = n1 + wc + ni*16 + fr;
    const float bv = (bias0 ? bias0[col] : 0.f) + (bias1 ? bias1[col] : 0.f);
    #pragma unroll
    for (int mi=0; mi<4; mi++){
      const int row0 = m1 + wr + mi*16 + fq*4;
      #pragma unroll
      for (int j=0; j<4; j++)
        C[(size_t)(row0 + j)*ldc + col] = acc[mi][ni][j] + bv;
    }
  }
}

// ---------------- decode fallback (A bf16, B f32): only when ws too small ----------------
__global__ __launch_bounds__(256) void k_gemm_dec(
    const unsigned short* __restrict__ A, const float* __restrict__ B,
    const float* __restrict__ bias, float* __restrict__ C){
  __shared__ __align__(16) unsigned short As[128][40];
  __shared__ __align__(16) unsigned short Bs[128][40];
  const int m1 = blockIdx.x*128, n1 = blockIdx.y*128;
  const int tid = threadIdx.x;
  const int wave = tid >> 6, lane = tid & 63;
  const int wr = (wave >> 1) * 64, wc = (wave & 1) * 64;
  const int fr = lane & 15, fq = lane >> 4;

  f32x4 acc[4][4];
  #pragma unroll
  for (int i=0;i<4;i++)
    #pragma unroll
    for (int j=0;j<4;j++) acc[i][j] = (f32x4){0.f,0.f,0.f,0.f};

  const int sr = tid >> 1, sk = (tid & 1) * 16;
  const unsigned short* arow = A + (size_t)(m1+sr)*NINP;
  const float* brow = B + (size_t)(n1+sr)*NINP;

  for (int k0 = 0; k0 < NINP; k0 += 32){
    bf16x8 ap0 = *(const bf16x8*)(arow + k0 + sk);
    bf16x8 ap1 = *(const bf16x8*)(arow + k0 + sk + 8);
    float4 b0 = *(const float4*)(brow + k0 + sk);
    float4 b1 = *(const float4*)(brow + k0 + sk + 4);
    float4 b2 = *(const float4*)(brow + k0 + sk + 8);
    float4 b3 = *(const float4*)(brow + k0 + sk + 12);
    bf16x8 bp0, bp1;
    bp0[0]=f2bf(b0.x); bp0[1]=f2bf(b0.y); bp0[2]=f2bf(b0.z); bp0[3]=f2bf(b0.w);
    bp0[4]=f2bf(b1.x); bp0[5]=f2bf(b1.y); bp0[6]=f2bf(b1.z); bp0[7]=f2bf(b1.w);
    bp1[0]=f2bf(b2.x); bp1[1]=f2bf(b2.y); bp1[2]=f2bf(b2.z); bp1[3]=f2bf(b2.w);
    bp1[4]=f2bf(b3.x); bp1[5]=f2bf(b3.y); bp1[6]=f2bf(b3.z); bp1[7]=f2bf(b3.w);

    __syncthreads();
    *(bf16x8*)&As[sr][sk]     = ap0;
    *(bf16x8*)&As[sr][sk + 8] = ap1;
    *(bf16x8*)&Bs[sr][sk]     = bp0;
    *(bf16x8*)&Bs[sr][sk + 8] = bp1;
    __syncthreads();

    bf16x8 af[4], bf[4];
    #pragma unroll
    for (int mi=0; mi<4; mi++) af[mi] = *(const bf16x8*)&As[wr + mi*16 + fr][fq*8];
    #pragma unroll
    for (int ni=0; ni<4; ni++) bf[ni] = *(const bf16x8*)&Bs[wc + ni*16 + fr][fq*8];
    #pragma unroll
    for (int mi=0; mi<4; mi++)
      #pragma unroll
      for (int ni=0; ni<4; ni++)
        acc[mi][ni] = __builtin_amdgcn_mfma_f32_16x16x32_bf16(af[mi], bf[ni], acc[mi][ni], 0, 0, 0);
  }

  #pragma unroll
  for (int ni=0; ni<4; ni++){
    const int col = n1 + wc + ni*16 + fr;
    const float bv = bias[col];
    #pragma unroll
    for (int mi=0; mi<4; mi++){
      const int row0 = m1 + wr + mi*16 + fq*4;
      #pragma unroll
      for (int j=0; j<4; j++)
        C[(size_t)(row0 + j)*NVOCAB + col] = acc[mi][ni][j] + bv;
    }
  }
}

// ---------------- logit_base[t][b][p] = emb.pol_w[p] + pol_b[p] + conv_b[p/11] ----------------
__global__ __launch_bounds__(256) void k_xp(const float* __restrict__ enc,
    const int* __restrict__ inputs, const float* __restrict__ pol_w,
    const float* __restrict__ pol_b, const float* __restrict__ conv_b,
    float* __restrict__ logit_base){
  const int m = blockIdx.x;
  const float* x = enc + (size_t)inputs[m]*NINP;
  __shared__ float xs[NINP];
  for (int i=threadIdx.x; i<NINP; i+=256) xs[i] = x[i];
  __syncthreads();
  const int wave = threadIdx.x >> 6, lane = threadIdx.x & 63;
  for (int p = wave; p < NPOL; p += 4){
    const float* w = pol_w + (size_t)p*NINP;
    float s = 0.f;
    for (int k=lane; k<NINP; k+=64) s = fmaf(xs[k], w[k], s);
    #pragma unroll
    for (int off=32; off; off>>=1) s += __shfl_down(s, off);
    if (lane==0) logit_base[(size_t)m*NPOL + p] = s + pol_b[p] + conv_b[p/11];
  }
}

// ===== barrier primitives (R10/R13-proven): per-gate-block flags, release/acquire fences =====
#define ARRIVE(ID, VAL)                                                                 \
  __syncthreads();                                                                      \
  if (tid == 0){                                                                        \
    __builtin_amdgcn_fence(__ATOMIC_RELEASE, "agent");                                  \
    __hip_atomic_store(flags + (ID)*16, (VAL), __ATOMIC_RELAXED, __HIP_MEMORY_SCOPE_AGENT); \
  }
#define WAITH_S(VAL, SLP)                                                               \
  if (tid < 64){                                                                        \
    int v_ = __hip_atomic_load(flags + tid*16, __ATOMIC_RELAXED, __HIP_MEMORY_SCOPE_AGENT); \
    while (__ballot(v_ < (VAL)) != 0ull){                                               \
      __builtin_amdgcn_s_sleep(SLP);                                                    \
      v_ = __hip_atomic_load(flags + tid*16, __ATOMIC_RELAXED, __HIP_MEMORY_SCOPE_AGENT); \
    }                                                                                   \
    if (tid == 0) __builtin_amdgcn_fence(__ATOMIC_ACQUIRE, "agent");                    \
  }                                                                                     \
  __syncthreads();
#define WAITH(VAL) WAITH_S(VAL, 1)

// ---------------- persistent kernel: 64 gate + 32 mem + (overlap) 160 decode blocks ----------------
// part=1: roles partitioned by XCD (blk&7): gate on XCD 0-1, mem on XCD 2, decode on XCD 3-7.
// Decode's acquire-invalidates and load streams never touch the scan XCDs' L2s.
__global__ __launch_bounds__(256, 1) void k_scan(
    const float* __restrict__ xg, const unsigned short* __restrict__ w_swz,
    const float* __restrict__ conv_w, const float* __restrict__ lbase,
    unsigned int* __restrict__ hsx, const float* __restrict__ c0,
    const float* __restrict__ m0, float* __restrict__ ot, int* __restrict__ flags,
    const unsigned short* __restrict__ enc_bf, const float* __restrict__ dbias,
    float* __restrict__ Cout, const float* __restrict__ enc, int part){
  const int blk = blockIdx.x, tid = threadIdx.x;

  int role, rid;
  if (part){
    const int xcd = blk & 7, slot = blk >> 3;
    if (xcd < 2)      { role = 0; rid = slot*2 + xcd; }     // 64 gate blocks
    else if (xcd == 2){ role = 1; rid = slot; }             // 32 mem blocks
    else              { role = 2; rid = slot*5 + (xcd-3); } // 160 decode blocks
  } else {
    role = (blk < NGB) ? 0 : 1;
    rid  = (blk < NGB) ? blk : (blk - NGB);
  }

  __shared__ __align__(16) unsigned short hlds[32*1024];
  __shared__ float gl[32][68];

  if (role == 0){
    // =================== gate block (R13-proven) ===================
    const int gid = rid;
    const int wv = tid >> 6, lane = tid & 63;
    const int fr = lane & 15, fq = lane >> 4;
    const int n0 = gid * 16;
    bf16x8 wreg[32];
    {
      const unsigned short* wb = w_swz + ((size_t)(wv*64 + gid)*32*64 + (size_t)lane)*8;
      #pragma unroll
      for (int ks=0; ks<32; ks++) wreg[ks] = *(const bf16x8*)(wb + (size_t)ks*512);
    }
    const int eb = tid >> 3, ej0 = (tid & 7)*2, en0 = n0 + ej0;
    float creg0 = c0[eb*NINP + en0], creg1 = c0[eb*NINP + en0 + 1];

    for (int t=0; t<SEQ; ++t){
      const float* xr = xg + ((size_t)t*BATCH + eb)*NGATE + en0;
      const float2 x_i = *(const float2*)(xr);
      const float2 x_f = *(const float2*)(xr + NINP);
      const float2 x_g = *(const float2*)(xr + 2*NINP);
      const float2 x_o = *(const float2*)(xr + 3*NINP);

      WAITH(t)

      {
        const unsigned short* hsrc = (const unsigned short*)(hsx + (size_t)t*16384);
        const int sb = tid >> 3, seg = tid & 7;
        const bf16x8* src = (const bf16x8*)(hsrc + sb*NINP);
        #pragma unroll
        for (int i=0;i<16;i++){
          int ch = seg*16 + i;
          ((bf16x8*)hlds)[sb*128 + (ch ^ (sb&7))] = src[ch];
        }
      }
      __syncthreads();

      f32x4 acc0 = {0.f,0.f,0.f,0.f}, acc1 = {0.f,0.f,0.f,0.f};
      #pragma unroll
      for (int ks=0; ks<32; ks++){
        bf16x8 a0 = ((const bf16x8*)hlds)[fr*128      + ((ks*4 + fq) ^ (fr&7))];
        bf16x8 a1 = ((const bf16x8*)hlds)[(16+fr)*128 + ((ks*4 + fq) ^ (fr&7))];
        acc0 = __builtin_amdgcn_mfma_f32_16x16x32_bf16(a0, wreg[ks], acc0, 0,0,0);
        acc1 = __builtin_amdgcn_mfma_f32_16x16x32_bf16(a1, wreg[ks], acc1, 0,0,0);
      }
      #pragma unroll
      for (int r=0;r<4;r++){
        gl[fq*4 + r][wv*16 + fr]      = acc0[r];
        gl[16 + fq*4 + r][wv*16 + fr] = acc1[r];
      }
      __syncthreads();

      {
        float gi0 = sigf (gl[eb][ej0]      + x_i.x), gi1 = sigf (gl[eb][ej0+1]      + x_i.y);
        float gf0 = sigf (gl[eb][16+ej0]   + x_f.x), gf1 = sigf (gl[eb][16+ej0+1]   + x_f.y);
        float gg0 = tanhf(gl[eb][32+ej0]   + x_g.x), gg1 = tanhf(gl[eb][32+ej0+1]   + x_g.y);
        float go0 = sigf (gl[eb][48+ej0]   + x_o.x), go1 = sigf (gl[eb][48+ej0+1]   + x_o.y);
        float cc0 = gf0*creg0 + gi0*gg0,  cc1 = gf1*creg1 + gi1*gg1;
        float hh0 = go0*tanhf(cc0),       hh1 = go1*tanhf(cc1);
        creg0 = cc0; creg1 = cc1;
        unsigned int pk = (unsigned int)f2bf(hh0) | ((unsigned int)f2bf(hh1) << 16);
        hsx[(size_t)(t+1)*16384 + eb*512 + (en0>>1)] = pk;
        if (t == SEQ-1){
          ot[eb*NINP + en0] = hh0;  ot[eb*NINP + en0 + 1] = hh1;             // hT
          ot[BATCH*NINP + eb*NINP + en0] = cc0;                              // cT
          ot[BATCH*NINP + eb*NINP + en0 + 1] = cc1;
        }
      }
      ARRIVE(gid, t+1)
    }
  } else if (role == 1) {
    // =================== mem block (R13-proven) ===================
    const int b = rid;
    const int wv = tid >> 6, lane = tid & 63;
    const int col0 = tid*4;
    __shared__ float red[NPOL][4];
    __shared__ float sp[NPOL];
    float m[4][DEPTH];
    #pragma unroll
    for (int c=0;c<4;c++)
      #pragma unroll
      for (int d=0;d<DEPTH;d++) m[c][d] = m0[(size_t)b*DEPTH*NINP + d*NINP + col0 + c];
    float cw0[2][4], cw1[2][4];
    #pragma unroll
    for (int o=0;o<2;o++)
      #pragma unroll
      for (int c=0;c<4;c++){
        cw0[o][c] = conv_w[o*2*NINP + 2*(col0+c)];
        cw1[o][c] = conv_w[o*2*NINP + 2*(col0+c) + 1];
      }

    for (int t=0; t<SEQ; ++t){
      float lp[NPOL];
      #pragma unroll
      for (int o=0;o<2;o++)
        #pragma unroll
        for (int tp=0; tp<11; tp++){
          float v = 0.f;
          #pragma unroll
          for (int c=0;c<4;c++){
            if (tp < DEPTH)   v = fmaf(m[c][tp],   cw0[o][c], v);
            if (tp+1 < DEPTH) v = fmaf(m[c][tp+1], cw1[o][c], v);
          }
          lp[o*11+tp] = v;
        }
      #pragma unroll
      for (int p=0;p<NPOL;p++){
        #pragma unroll
        for (int off=32; off; off>>=1) lp[p] += __shfl_down(lp[p], off);
      }
      if (lane == 0){
        #pragma unroll
        for (int p=0;p<NPOL;p++) red[p][wv] = lp[p];
      }
      __syncthreads();
      if (tid == 0){
        float l[NPOL]; float mx = -1e30f;
        #pragma unroll
        for (int p=0;p<NPOL;p++){
          l[p] = red[p][0]+red[p][1]+red[p][2]+red[p][3]
               + lbase[(size_t)t*(BATCH*NPOL) + b*NPOL + p];
          mx = fmaxf(mx, l[p]);
        }
        float sum = 0.f;
        #pragma unroll
        for (int p=0;p<NPOL;p++){ l[p] = expf(l[p]-mx); sum += l[p]; }
        float inv = 1.f/sum;
        #pragma unroll
        for (int p=0;p<NPOL;p++) sp[p] = l[p]*inv;
      }
      WAITH(t+1)

      const unsigned short* hsrc = (const unsigned short*)(hsx + (size_t)(t+1)*16384);
      unsigned long long hv = *(const unsigned long long*)(hsrc + b*NINP + col0);
      float hc[4];
      hc[0] = bf2f((unsigned short)hv);
      hc[1] = bf2f((unsigned short)(hv >> 16));
      hc[2] = bf2f((unsigned short)(hv >> 32));
      hc[3] = bf2f((unsigned short)(hv >> 48));

      float psum = 0.f;
      #pragma unroll
      for (int k2=11;k2<22;k2++) psum += sp[k2];
      #pragma unroll
      for (int c=0;c<4;c++){
        float outv[DEPTH];
        {
          float v = psum*hc[c];
          #pragma unroll
          for (int jj=0;jj<DEPTH;jj++) v = fmaf(sp[jj], m[c][jj], v);
          outv[0] = v;
        }
        #pragma unroll
        for (int d=1; d<DEPTH; d++){
          float v = 0.f;
          for (int jj=d;   jj<DEPTH; jj++) v = fmaf(sp[jj-d],    m[c][jj], v);
          for (int jj=d-1; jj<DEPTH; jj++) v = fmaf(sp[12+jj-d], m[c][jj], v);
          outv[d] = v;
        }
        #pragma unroll
        for (int d=0;d<DEPTH;d++) m[c][d] = outv[d];
      }
      __syncthreads();
      if (t == SEQ-1){
        #pragma unroll
        for (int c=0;c<4;c++)
          #pragma unroll
          for (int d=0;d<DEPTH;d++)
            ot[2*BATCH*NINP + (size_t)b*DEPTH*NINP + d*NINP + col0 + c] = m[c][d];
      }
    }
  } else {
    // =================== decode block (XCD 3-7): enc conversion + BK=128 GEMM ===================
    const int dBlk = rid;
    int* ecnt = flags + 1024;

    // --- one-time prologue: enc f32 -> bf16 (replaces the k_enc prefix kernel) ---
    {
      unsigned short* ebw = (unsigned short*)enc_bf;   // write view
      for (int it = dBlk*256 + tid; it < 2048000; it += NDB*256){
        const float* s = enc + (size_t)it*16;
        float4 a0 = *(const float4*)(s);
        float4 a1 = *(const float4*)(s+4);
        float4 a2 = *(const float4*)(s+8);
        float4 a3 = *(const float4*)(s+12);
        bf16x8 o0, o1;
        o0[0]=f2bf(a0.x); o0[1]=f2bf(a0.y); o0[2]=f2bf(a0.z); o0[3]=f2bf(a0.w);
        o0[4]=f2bf(a1.x); o0[5]=f2bf(a1.y); o0[6]=f2bf(a1.z); o0[7]=f2bf(a1.w);
        o1[0]=f2bf(a2.x); o1[1]=f2bf(a2.y); o1[2]=f2bf(a2.z); o1[3]=f2bf(a2.w);
        o1[4]=f2bf(a3.x); o1[5]=f2bf(a3.y); o1[6]=f2bf(a3.z); o1[7]=f2bf(a3.w);
        *(bf16x8*)(ebw + (size_t)it*16)     = o0;
        *(bf16x8*)(ebw + (size_t)it*16 + 8) = o1;
      }
      __syncthreads();
      if (tid == 0){
        __builtin_amdgcn_fence(__ATOMIC_RELEASE, "agent");
        __hip_atomic_fetch_add(ecnt, 1, __ATOMIC_RELAXED, __HIP_MEMORY_SCOPE_AGENT);
        while (__hip_atomic_load(ecnt, __ATOMIC_RELAXED, __HIP_MEMORY_SCOPE_AGENT) < NDB)
          __builtin_amdgcn_s_sleep(8);
        __builtin_amdgcn_fence(__ATOMIC_ACQUIRE, "agent");
      }
      __syncthreads();
    }

    // --- BK=128 decode GEMM, gated by scan progress ---
    const int wave = tid >> 6, lane = tid & 63;
    const int wr = (wave >> 1) * 64, wc = (wave & 1) * 64;
    const int fr = lane & 15, fq = lane >> 4;
    unsigned short* As = (unsigned short*)hlds;          // [128][128]
    unsigned short* Bs = As + 128*128;
    const unsigned short* hsA = (const unsigned short*)(hsx + 16384);
    const int srow0 = wave*32;
    const int lrow = lane >> 4;
    const int lch  = lane & 15;
    int fenced = 0;

    for (int tile = dBlk; tile < 32*250; tile += NDB){
      const int mt = tile/250, nt = tile - mt*250;
      const int req = 4*mt + 4;
      if (req > fenced){ WAITH_S(req, 8); fenced = req; }
      const int m1 = mt*128, n1 = nt*128;

      f32x4 acc[4][4];
      #pragma unroll
      for (int i=0;i<4;i++)
        #pragma unroll
        for (int j=0;j<4;j++) acc[i][j] = (f32x4){0.f,0.f,0.f,0.f};

      for (int k0 = 0; k0 < NINP; k0 += 128){
        __syncthreads();
        #pragma unroll
        for (int j=0;j<8;j++){
          const int r = srow0 + j*4 + lrow;
          const unsigned short* gA = hsA + (size_t)(m1 + r)*NINP + k0 + (lch ^ (r&7))*8;
          __builtin_amdgcn_global_load_lds((const unsigned int*)gA,
              (unsigned int*)(As + (size_t)(srow0 + j*4)*128), 16, 0, 0);
        }
        #pragma unroll
        for (int j=0;j<8;j++){
          const int r = srow0 + j*4 + lrow;
          const unsigned short* gB = enc_bf + (size_t)(n1 + r)*NINP + k0 + (lch ^ (r&7))*8;
          __builtin_amdgcn_global_load_lds((const unsigned int*)gB,
              (unsigned int*)(Bs + (size_t)(srow0 + j*4)*128), 16, 0, 0);
        }
        __syncthreads();

        #pragma unroll
        for (int ks=0; ks<4; ks++){
          bf16x8 af[4], bf[4];
          #pragma unroll
          for (int mi=0; mi<4; mi++){
            const int r = wr + mi*16 + fr;
            af[mi] = *(const bf16x8*)(As + (size_t)r*128 + ((ks*4 + fq) ^ (r&7))*8);
          }
          #pragma unroll
          for (int ni=0; ni<4; ni++){
            const int r = wc + ni*16 + fr;
            bf[ni] = *(const bf16x8*)(Bs + (size_t)r*128 + ((ks*4 + fq) ^ (r&7))*8);
          }
          #pragma unroll
          for (int mi=0; mi<4; mi++)
            #pragma unroll
            for (int ni=0; ni<4; ni++)
              acc[mi][ni] = __builtin_amdgcn_mfma_f32_16x16x32_bf16(af[mi], bf[ni], acc[mi][ni], 0, 0, 0);
        }
      }

      #pragma unroll
      for (int ni=0; ni<4; ni++){
        const int col = n1 + wc + ni*16 + fr;
        const float bv = dbias[col];
        #pragma unroll
        for (int mi=0; mi<4; mi++){
          const int row0 = m1 + wr + mi*16 + fq*4;
          #pragma unroll
          for (int j=0; j<4; j++)
            Cout[(size_t)(row0 + j)*NVOCAB + col] = acc[mi][ni][j] + bv;
        }
      }
    }
  }
}

extern "C" void kernel_launch(void* const* d_in, const int* in_sizes, int n_in,
                              void* d_out, int out_size, void* d_ws, size_t ws_size,
                              hipStream_t stream){
  (void)in_sizes; (void)n_in; (void)out_size;
  const int*   inputs = (const int*)  d_in[0];
  const float* h0     = (const float*)d_in[1];
  const float* c0     = (const float*)d_in[2];
  const float* m0     = (const float*)d_in[3];
  const float* enc    = (const float*)d_in[4];
  const float* dbias  = (const float*)d_in[5];
  const float* w_ih   = (const float*)d_in[6];
  const float* w_hh   = (const float*)d_in[7];
  const float* b_ih   = (const float*)d_in[8];
  const float* b_hh   = (const float*)d_in[9];
  const float* conv_w = (const float*)d_in[10];
  const float* conv_b = (const float*)d_in[11];
  const float* pol_w  = (const float*)d_in[12];
  const float* pol_b  = (const float*)d_in[13];

  float* out = (float*)d_out;
  float* ws  = (float*)d_ws;
  // ws layout (f32 slots): lbase 90112 | hsx 2,113,536 | enc_bf 16,384,000 | flags 1040
  float* lbase = ws;
  unsigned int* hsx = (unsigned int*)(ws + 90112);
  unsigned short* hs_bf  = (unsigned short*)(hsx + 16384);      // slots 1..128 = h(0..127)
  unsigned short* enc_bf = (unsigned short*)(ws + 90112 + 2113536);
  int* flags_ws          = (int*)(ws + 90112 + 2113536 + 16384000);
  const int overlap = (ws_size >= (size_t)18600000*4);
  float* xg = overlap ? (out + XG_OFF) : out;
  unsigned short* w_swz = (unsigned short*)(out + 17000000);    // 4 MB (read once at scan start)
  int* flags = overlap ? flags_ws : (int*)(out + 19600000);
  float* ot = out + DEC_OFF;                                    // hT | cT | memT

  k_init<<<64, 256, 0, stream>>>(h0, hsx);
  k_wconv<<<2048, 256, 0, stream>>>(w_hh, w_swz);

  // xg[m,j] = emb(m).w_ih[j] + b_ih[j] + b_hh[j]   (4096x4096x1024 bf16 MFMA)
  dim3 gxg(32, 32);
  k_gemm_bf16<<<gxg, 256, 0, stream>>>(enc, inputs, w_ih, b_ih, b_hh, xg, NINP, NGATE);

  k_xp<<<SEQ*BATCH, 256, 0, stream>>>(enc, inputs, pol_w, pol_b, conv_b, lbase);

  hipMemsetAsync(flags, 0, (64*16 + 16)*sizeof(int), stream);

  const int nblk = overlap ? (NGB + NMB + NDB) : (NGB + NMB);
  k_scan<<<nblk, 256, 0, stream>>>(xg, w_swz, conv_w, lbase, hsx, c0, m0,
                                   ot, flags, enc_bf, dbias, out, enc, overlap);

  if (!overlap){
    dim3 gdec(32, 250);
    k_gemm_dec<<<gdec, 256, 0, stream>>>(hs_bf, enc, dbias, out);
  }
}

// Round 18
// 1383.099 us; speedup vs baseline: 1.6334x; 1.6334x over previous
//
#include <hip/hip_runtime.h>
#include <math.h>

#define SEQ    128
#define BATCH  32
#define NINP   1024
#define NGATE  4096   // 4*NINP
#define DEPTH  10
#define NPOL   22     // 2*(DEPTH+1)
#define NVOCAB 32000
#define DEC_OFF 131072000ll   // SEQ*BATCH*NVOCAB
#define NGB    64             // gate blocks (blk 0-63  -> XCD 0-1 under chunked dispatch)
#define NMB    32             // mem blocks  (blk 64-95 -> XCD 2)
#define NDB    160            // decode blocks (blk 96-255 -> XCD 3-7)
#define XG_OFF 114294784      // DEC_OFF - 16777216: xg in the TAIL of decoded (rows 3572+)

typedef __attribute__((ext_vector_type(8))) short bf16x8;
typedef __attribute__((ext_vector_type(4))) float f32x4;

__device__ __forceinline__ float sigf(float x){ return 1.0f/(1.0f + expf(-x)); }

__device__ __forceinline__ unsigned short f2bf(float x){
  unsigned int u = __float_as_uint(x);
  unsigned int r = (u + 0x7FFFu + ((u >> 16) & 1u)) >> 16;   // RNE
  return (unsigned short)r;
}
__device__ __forceinline__ float bf2f(unsigned short u){
  return __uint_as_float(((unsigned int)u) << 16);
}

// ---------------- init: h0 -> packed bf16 pairs into hsx slot 0 ----------------
__global__ __launch_bounds__(256) void k_init(const float* __restrict__ h0,
    unsigned int* __restrict__ hsx0){
  int i = blockIdx.x*256 + threadIdx.x;   // < 16384
  unsigned int u = (unsigned int)f2bf(h0[2*i]) | ((unsigned int)f2bf(h0[2*i+1]) << 16);
  hsx0[i] = u;                            // layout: b*512 + n/2
}

// ---------------- w_hh -> bf16, swizzled to per-wave MFMA fragment layout ----------------
__global__ __launch_bounds__(256) void k_wconv(const float* __restrict__ w_hh,
    unsigned short* __restrict__ w_swz){
  int id = blockIdx.x*256 + threadIdx.x;          // 0..524287
  int lane = id & 63, kc = (id>>6)&7, kq = (id>>9)&3, nt = id>>11;
  int j = nt*16 + (lane&15);
  int k = kq*256 + kc*32 + (lane>>4)*8;
  const float* src = w_hh + (size_t)j*NINP + k;
  bf16x8 d;
  #pragma unroll
  for (int e=0;e<8;e++) d[e] = (short)f2bf(src[e]);
  *(bf16x8*)(w_swz + (size_t)id*8) = d;
}

// ---------------- bf16 MFMA GEMM (f32 sources, reg-staged): C = A.B^T + bias ----------------
__global__ __launch_bounds__(256) void k_gemm_bf16(
    const float* __restrict__ A, const int* __restrict__ Aidx,
    const float* __restrict__ B, const float* __restrict__ bias0,
    const float* __restrict__ bias1, float* __restrict__ C,
    int K, int ldc){
  __shared__ __align__(16) unsigned short As[128][40];
  __shared__ __align__(16) unsigned short Bs[128][40];
  const int m1 = blockIdx.y*128, n1 = blockIdx.x*128;
  const int tid = threadIdx.x;
  const int wave = tid >> 6, lane = tid & 63;
  const int wr = (wave >> 1) * 64, wc = (wave & 1) * 64;
  const int fr = lane & 15, fq = lane >> 4;

  f32x4 acc[4][4];
  #pragma unroll
  for (int i=0;i<4;i++)
    #pragma unroll
    for (int j=0;j<4;j++) acc[i][j] = (f32x4){0.f,0.f,0.f,0.f};

  const int sr = tid >> 1, sk = (tid & 1) * 16;
  const float* arow = Aidx ? (A + (size_t)Aidx[m1+sr]*K) : (A + (size_t)(m1+sr)*K);
  const float* brow = B + (size_t)(n1+sr)*K;

  for (int k0 = 0; k0 < K; k0 += 32){
    float4 a0 = *(const float4*)(arow + k0 + sk);
    float4 a1 = *(const float4*)(arow + k0 + sk + 4);
    float4 a2 = *(const float4*)(arow + k0 + sk + 8);
    float4 a3 = *(const float4*)(arow + k0 + sk + 12);
    float4 b0 = *(const float4*)(brow + k0 + sk);
    float4 b1 = *(const float4*)(brow + k0 + sk + 4);
    float4 b2 = *(const float4*)(brow + k0 + sk + 8);
    float4 b3 = *(const float4*)(brow + k0 + sk + 12);
    bf16x8 ap0, ap1, bp0, bp1;
    ap0[0]=f2bf(a0.x); ap0[1]=f2bf(a0.y); ap0[2]=f2bf(a0.z); ap0[3]=f2bf(a0.w);
    ap0[4]=f2bf(a1.x); ap0[5]=f2bf(a1.y); ap0[6]=f2bf(a1.z); ap0[7]=f2bf(a1.w);
    ap1[0]=f2bf(a2.x); ap1[1]=f2bf(a2.y); ap1[2]=f2bf(a2.z); ap1[3]=f2bf(a2.w);
    ap1[4]=f2bf(a3.x); ap1[5]=f2bf(a3.y); ap1[6]=f2bf(a3.z); ap1[7]=f2bf(a3.w);
    bp0[0]=f2bf(b0.x); bp0[1]=f2bf(b0.y); bp0[2]=f2bf(b0.z); bp0[3]=f2bf(b0.w);
    bp0[4]=f2bf(b1.x); bp0[5]=f2bf(b1.y); bp0[6]=f2bf(b1.z); bp0[7]=f2bf(b1.w);
    bp1[0]=f2bf(b2.x); bp1[1]=f2bf(b2.y); bp1[2]=f2bf(b2.z); bp1[3]=f2bf(b2.w);
    bp1[4]=f2bf(b3.x); bp1[5]=f2bf(b3.y); bp1[6]=f2bf(b3.z); bp1[7]=f2bf(b3.w);

    __syncthreads();
    *(bf16x8*)&As[sr][sk]     = ap0;
    *(bf16x8*)&As[sr][sk + 8] = ap1;
    *(bf16x8*)&Bs[sr][sk]     = bp0;
    *(bf16x8*)&Bs[sr][sk + 8] = bp1;
    __syncthreads();

    bf16x8 af[4], bf[4];
    #pragma unroll
    for (int mi=0; mi<4; mi++) af[mi] = *(const bf16x8*)&As[wr + mi*16 + fr][fq*8];
    #pragma unroll
    for (int ni=0; ni<4; ni++) bf[ni] = *(const bf16x8*)&Bs[wc + ni*16 + fr][fq*8];
    #pragma unroll
    for (int mi=0; mi<4; mi++)
      #pragma unroll
      for (int ni=0; ni<4; ni++)
        acc[mi][ni] = __builtin_amdgcn_mfma_f32_16x16x32_bf16(af[mi], bf[ni], acc[mi][ni], 0, 0, 0);
  }

  #pragma unroll
  for (int ni=0; ni<4; ni++){
    const int col = n1 + wc + ni*16 + fr;
    const float bv = (bias0 ? bias0[col] : 0.f) + (bias1 ? bias1[col] : 0.f);
    #pragma unroll
    for (int mi=0; mi<4; mi++){
      const int row0 = m1 + wr + mi*16 + fq*4;
      #pragma unroll
      for (int j=0; j<4; j++)
        C[(size_t)(row0 + j)*ldc + col] = acc[mi][ni][j] + bv;
    }
  }
}

// ---------------- decode fallback (A bf16, B f32): only when ws too small ----------------
__global__ __launch_bounds__(256) void k_gemm_dec(
    const unsigned short* __restrict__ A, const float* __restrict__ B,
    const float* __restrict__ bias, float* __restrict__ C){
  __shared__ __align__(16) unsigned short As[128][40];
  __shared__ __align__(16) unsigned short Bs[128][40];
  const int m1 = blockIdx.x*128, n1 = blockIdx.y*128;
  const int tid = threadIdx.x;
  const int wave = tid >> 6, lane = tid & 63;
  const int wr = (wave >> 1) * 64, wc = (wave & 1) * 64;
  const int fr = lane & 15, fq = lane >> 4;

  f32x4 acc[4][4];
  #pragma unroll
  for (int i=0;i<4;i++)
    #pragma unroll
    for (int j=0;j<4;j++) acc[i][j] = (f32x4){0.f,0.f,0.f,0.f};

  const int sr = tid >> 1, sk = (tid & 1) * 16;
  const unsigned short* arow = A + (size_t)(m1+sr)*NINP;
  const float* brow = B + (size_t)(n1+sr)*NINP;

  for (int k0 = 0; k0 < NINP; k0 += 32){
    bf16x8 ap0 = *(const bf16x8*)(arow + k0 + sk);
    bf16x8 ap1 = *(const bf16x8*)(arow + k0 + sk + 8);
    float4 b0 = *(const float4*)(brow + k0 + sk);
    float4 b1 = *(const float4*)(brow + k0 + sk + 4);
    float4 b2 = *(const float4*)(brow + k0 + sk + 8);
    float4 b3 = *(const float4*)(brow + k0 + sk + 12);
    bf16x8 bp0, bp1;
    bp0[0]=f2bf(b0.x); bp0[1]=f2bf(b0.y); bp0[2]=f2bf(b0.z); bp0[3]=f2bf(b0.w);
    bp0[4]=f2bf(b1.x); bp0[5]=f2bf(b1.y); bp0[6]=f2bf(b1.z); bp0[7]=f2bf(b1.w);
    bp1[0]=f2bf(b2.x); bp1[1]=f2bf(b2.y); bp1[2]=f2bf(b2.z); bp1[3]=f2bf(b2.w);
    bp1[4]=f2bf(b3.x); bp1[5]=f2bf(b3.y); bp1[6]=f2bf(b3.z); bp1[7]=f2bf(b3.w);

    __syncthreads();
    *(bf16x8*)&As[sr][sk]     = ap0;
    *(bf16x8*)&As[sr][sk + 8] = ap1;
    *(bf16x8*)&Bs[sr][sk]     = bp0;
    *(bf16x8*)&Bs[sr][sk + 8] = bp1;
    __syncthreads();

    bf16x8 af[4], bf[4];
    #pragma unroll
    for (int mi=0; mi<4; mi++) af[mi] = *(const bf16x8*)&As[wr + mi*16 + fr][fq*8];
    #pragma unroll
    for (int ni=0; ni<4; ni++) bf[ni] = *(const bf16x8*)&Bs[wc + ni*16 + fr][fq*8];
    #pragma unroll
    for (int mi=0; mi<4; mi++)
      #pragma unroll
      for (int ni=0; ni<4; ni++)
        acc[mi][ni] = __builtin_amdgcn_mfma_f32_16x16x32_bf16(af[mi], bf[ni], acc[mi][ni], 0, 0, 0);
  }

  #pragma unroll
  for (int ni=0; ni<4; ni++){
    const int col = n1 + wc + ni*16 + fr;
    const float bv = bias[col];
    #pragma unroll
    for (int mi=0; mi<4; mi++){
      const int row0 = m1 + wr + mi*16 + fq*4;
      #pragma unroll
      for (int j=0; j<4; j++)
        C[(size_t)(row0 + j)*NVOCAB + col] = acc[mi][ni][j] + bv;
    }
  }
}

// ---------------- logit_base[t][b][p] = emb.pol_w[p] + pol_b[p] + conv_b[p/11] ----------------
__global__ __launch_bounds__(256) void k_xp(const float* __restrict__ enc,
    const int* __restrict__ inputs, const float* __restrict__ pol_w,
    const float* __restrict__ pol_b, const float* __restrict__ conv_b,
    float* __restrict__ logit_base){
  const int m = blockIdx.x;
  const float* x = enc + (size_t)inputs[m]*NINP;
  __shared__ float xs[NINP];
  for (int i=threadIdx.x; i<NINP; i+=256) xs[i] = x[i];
  __syncthreads();
  const int wave = threadIdx.x >> 6, lane = threadIdx.x & 63;
  for (int p = wave; p < NPOL; p += 4){
    const float* w = pol_w + (size_t)p*NINP;
    float s = 0.f;
    for (int k=lane; k<NINP; k+=64) s = fmaf(xs[k], w[k], s);
    #pragma unroll
    for (int off=32; off; off>>=1) s += __shfl_down(s, off);
    if (lane==0) logit_base[(size_t)m*NPOL + p] = s + pol_b[p] + conv_b[p/11];
  }
}

// ===== barrier primitives (R10/R13-proven): per-gate-block flags, release/acquire fences =====
#define ARRIVE(VAL)                                                                     \
  __syncthreads();                                                                      \
  if (tid == 0){                                                                        \
    __builtin_amdgcn_fence(__ATOMIC_RELEASE, "agent");                                  \
    __hip_atomic_store(flags + blk*16, (VAL), __ATOMIC_RELAXED, __HIP_MEMORY_SCOPE_AGENT); \
  }
#define WAITH_S(VAL, SLP)                                                               \
  if (tid < 64){                                                                        \
    int v_ = __hip_atomic_load(flags + tid*16, __ATOMIC_RELAXED, __HIP_MEMORY_SCOPE_AGENT); \
    while (__ballot(v_ < (VAL)) != 0ull){                                               \
      __builtin_amdgcn_s_sleep(SLP);                                                    \
      v_ = __hip_atomic_load(flags + tid*16, __ATOMIC_RELAXED, __HIP_MEMORY_SCOPE_AGENT); \
    }                                                                                   \
    if (tid == 0) __builtin_amdgcn_fence(__ATOMIC_ACQUIRE, "agent");                    \
  }                                                                                     \
  __syncthreads();
#define WAITH(VAL) WAITH_S(VAL, 1)

// ---------------- persistent kernel: 64 gate + 32 mem + (overlap) 160 decode blocks ----------------
// LINEAR role mapping (chunked dispatch co-locates consecutive blocks => natural XCD partition).
__global__ __launch_bounds__(256, 1) void k_scan(
    const float* __restrict__ xg, const unsigned short* __restrict__ w_swz,
    const float* __restrict__ conv_w, const float* __restrict__ lbase,
    unsigned int* __restrict__ hsx, const float* __restrict__ c0,
    const float* __restrict__ m0, float* __restrict__ ot, int* __restrict__ flags,
    const unsigned short* __restrict__ enc_bf, const float* __restrict__ dbias,
    float* __restrict__ Cout, const float* __restrict__ enc){
  const int blk = blockIdx.x, tid = threadIdx.x;

  __shared__ __align__(16) unsigned short hlds[32*1024];
  __shared__ float gl[32][68];

  if (blk < NGB){
    // =================== gate block (R13-proven) ===================
    const int wv = tid >> 6, lane = tid & 63;
    const int fr = lane & 15, fq = lane >> 4;
    const int n0 = blk * 16;
    bf16x8 wreg[32];
    {
      const unsigned short* wb = w_swz + ((size_t)(wv*64 + blk)*32*64 + (size_t)lane)*8;
      #pragma unroll
      for (int ks=0; ks<32; ks++) wreg[ks] = *(const bf16x8*)(wb + (size_t)ks*512);
    }
    const int eb = tid >> 3, ej0 = (tid & 7)*2, en0 = n0 + ej0;
    float creg0 = c0[eb*NINP + en0], creg1 = c0[eb*NINP + en0 + 1];

    for (int t=0; t<SEQ; ++t){
      const float* xr = xg + ((size_t)t*BATCH + eb)*NGATE + en0;
      const float2 x_i = *(const float2*)(xr);
      const float2 x_f = *(const float2*)(xr + NINP);
      const float2 x_g = *(const float2*)(xr + 2*NINP);
      const float2 x_o = *(const float2*)(xr + 3*NINP);

      WAITH(t)

      {
        const unsigned short* hsrc = (const unsigned short*)(hsx + (size_t)t*16384);
        const int sb = tid >> 3, seg = tid & 7;
        const bf16x8* src = (const bf16x8*)(hsrc + sb*NINP);
        #pragma unroll
        for (int i=0;i<16;i++){
          int ch = seg*16 + i;
          ((bf16x8*)hlds)[sb*128 + (ch ^ (sb&7))] = src[ch];
        }
      }
      __syncthreads();

      f32x4 acc0 = {0.f,0.f,0.f,0.f}, acc1 = {0.f,0.f,0.f,0.f};
      #pragma unroll
      for (int ks=0; ks<32; ks++){
        bf16x8 a0 = ((const bf16x8*)hlds)[fr*128      + ((ks*4 + fq) ^ (fr&7))];
        bf16x8 a1 = ((const bf16x8*)hlds)[(16+fr)*128 + ((ks*4 + fq) ^ (fr&7))];
        acc0 = __builtin_amdgcn_mfma_f32_16x16x32_bf16(a0, wreg[ks], acc0, 0,0,0);
        acc1 = __builtin_amdgcn_mfma_f32_16x16x32_bf16(a1, wreg[ks], acc1, 0,0,0);
      }
      #pragma unroll
      for (int r=0;r<4;r++){
        gl[fq*4 + r][wv*16 + fr]      = acc0[r];
        gl[16 + fq*4 + r][wv*16 + fr] = acc1[r];
      }
      __syncthreads();

      {
        float gi0 = sigf (gl[eb][ej0]      + x_i.x), gi1 = sigf (gl[eb][ej0+1]      + x_i.y);
        float gf0 = sigf (gl[eb][16+ej0]   + x_f.x), gf1 = sigf (gl[eb][16+ej0+1]   + x_f.y);
        float gg0 = tanhf(gl[eb][32+ej0]   + x_g.x), gg1 = tanhf(gl[eb][32+ej0+1]   + x_g.y);
        float go0 = sigf (gl[eb][48+ej0]   + x_o.x), go1 = sigf (gl[eb][48+ej0+1]   + x_o.y);
        float cc0 = gf0*creg0 + gi0*gg0,  cc1 = gf1*creg1 + gi1*gg1;
        float hh0 = go0*tanhf(cc0),       hh1 = go1*tanhf(cc1);
        creg0 = cc0; creg1 = cc1;
        unsigned int pk = (unsigned int)f2bf(hh0) | ((unsigned int)f2bf(hh1) << 16);
        hsx[(size_t)(t+1)*16384 + eb*512 + (en0>>1)] = pk;
        if (t == SEQ-1){
          ot[eb*NINP + en0] = hh0;  ot[eb*NINP + en0 + 1] = hh1;             // hT
          ot[BATCH*NINP + eb*NINP + en0] = cc0;                              // cT
          ot[BATCH*NINP + eb*NINP + en0 + 1] = cc1;
        }
      }
      ARRIVE(t+1)
    }
  } else if (blk < NGB + NMB) {
    // =================== mem block (R13-proven) ===================
    const int b = blk - NGB;
    const int wv = tid >> 6, lane = tid & 63;
    const int col0 = tid*4;
    __shared__ float red[NPOL][4];
    __shared__ float sp[NPOL];
    float m[4][DEPTH];
    #pragma unroll
    for (int c=0;c<4;c++)
      #pragma unroll
      for (int d=0;d<DEPTH;d++) m[c][d] = m0[(size_t)b*DEPTH*NINP + d*NINP + col0 + c];
    float cw0[2][4], cw1[2][4];
    #pragma unroll
    for (int o=0;o<2;o++)
      #pragma unroll
      for (int c=0;c<4;c++){
        cw0[o][c] = conv_w[o*2*NINP + 2*(col0+c)];
        cw1[o][c] = conv_w[o*2*NINP + 2*(col0+c) + 1];
      }

    for (int t=0; t<SEQ; ++t){
      float lp[NPOL];
      #pragma unroll
      for (int o=0;o<2;o++)
        #pragma unroll
        for (int tp=0; tp<11; tp++){
          float v = 0.f;
          #pragma unroll
          for (int c=0;c<4;c++){
            if (tp < DEPTH)   v = fmaf(m[c][tp],   cw0[o][c], v);
            if (tp+1 < DEPTH) v = fmaf(m[c][tp+1], cw1[o][c], v);
          }
          lp[o*11+tp] = v;
        }
      #pragma unroll
      for (int p=0;p<NPOL;p++){
        #pragma unroll
        for (int off=32; off; off>>=1) lp[p] += __shfl_down(lp[p], off);
      }
      if (lane == 0){
        #pragma unroll
        for (int p=0;p<NPOL;p++) red[p][wv] = lp[p];
      }
      __syncthreads();
      if (tid == 0){
        float l[NPOL]; float mx = -1e30f;
        #pragma unroll
        for (int p=0;p<NPOL;p++){
          l[p] = red[p][0]+red[p][1]+red[p][2]+red[p][3]
               + lbase[(size_t)t*(BATCH*NPOL) + b*NPOL + p];
          mx = fmaxf(mx, l[p]);
        }
        float sum = 0.f;
        #pragma unroll
        for (int p=0;p<NPOL;p++){ l[p] = expf(l[p]-mx); sum += l[p]; }
        float inv = 1.f/sum;
        #pragma unroll
        for (int p=0;p<NPOL;p++) sp[p] = l[p]*inv;
      }
      WAITH(t+1)

      const unsigned short* hsrc = (const unsigned short*)(hsx + (size_t)(t+1)*16384);
      unsigned long long hv = *(const unsigned long long*)(hsrc + b*NINP + col0);
      float hc[4];
      hc[0] = bf2f((unsigned short)hv);
      hc[1] = bf2f((unsigned short)(hv >> 16));
      hc[2] = bf2f((unsigned short)(hv >> 32));
      hc[3] = bf2f((unsigned short)(hv >> 48));

      float psum = 0.f;
      #pragma unroll
      for (int k2=11;k2<22;k2++) psum += sp[k2];
      #pragma unroll
      for (int c=0;c<4;c++){
        float outv[DEPTH];
        {
          float v = psum*hc[c];
          #pragma unroll
          for (int jj=0;jj<DEPTH;jj++) v = fmaf(sp[jj], m[c][jj], v);
          outv[0] = v;
        }
        #pragma unroll
        for (int d=1; d<DEPTH; d++){
          float v = 0.f;
          for (int jj=d;   jj<DEPTH; jj++) v = fmaf(sp[jj-d],    m[c][jj], v);
          for (int jj=d-1; jj<DEPTH; jj++) v = fmaf(sp[12+jj-d], m[c][jj], v);
          outv[d] = v;
        }
        #pragma unroll
        for (int d=0;d<DEPTH;d++) m[c][d] = outv[d];
      }
      __syncthreads();
      if (t == SEQ-1){
        #pragma unroll
        for (int c=0;c<4;c++)
          #pragma unroll
          for (int d=0;d<DEPTH;d++)
            ot[2*BATCH*NINP + (size_t)b*DEPTH*NINP + d*NINP + col0 + c] = m[c][d];
      }
    }
  } else {
    // =================== decode block: enc->bf16 prologue + BK=128 GEMM ===================
    const int dBlk = blk - (NGB + NMB);
    int* ecnt = flags + 1024;

    // one-time prologue: enc f32 -> bf16 (hides under the scan's first steps)
    {
      unsigned short* ebw = (unsigned short*)enc_bf;
      for (int it = dBlk*256 + tid; it < 2048000; it += NDB*256){
        const float* s = enc + (size_t)it*16;
        float4 a0 = *(const float4*)(s);
        float4 a1 = *(const float4*)(s+4);
        float4 a2 = *(const float4*)(s+8);
        float4 a3 = *(const float4*)(s+12);
        bf16x8 o0, o1;
        o0[0]=f2bf(a0.x); o0[1]=f2bf(a0.y); o0[2]=f2bf(a0.z); o0[3]=f2bf(a0.w);
        o0[4]=f2bf(a1.x); o0[5]=f2bf(a1.y); o0[6]=f2bf(a1.z); o0[7]=f2bf(a1.w);
        o1[0]=f2bf(a2.x); o1[1]=f2bf(a2.y); o1[2]=f2bf(a2.z); o1[3]=f2bf(a2.w);
        o1[4]=f2bf(a3.x); o1[5]=f2bf(a3.y); o1[6]=f2bf(a3.z); o1[7]=f2bf(a3.w);
        *(bf16x8*)(ebw + (size_t)it*16)     = o0;
        *(bf16x8*)(ebw + (size_t)it*16 + 8) = o1;
      }
      __syncthreads();
      if (tid == 0){
        __builtin_amdgcn_fence(__ATOMIC_RELEASE, "agent");
        __hip_atomic_fetch_add(ecnt, 1, __ATOMIC_RELAXED, __HIP_MEMORY_SCOPE_AGENT);
        while (__hip_atomic_load(ecnt, __ATOMIC_RELAXED, __HIP_MEMORY_SCOPE_AGENT) < NDB)
          __builtin_amdgcn_s_sleep(8);
        __builtin_amdgcn_fence(__ATOMIC_ACQUIRE, "agent");
      }
      __syncthreads();
    }

    // BK=128 decode GEMM, gated by scan progress (tile needs hsx slots <= 4mt+4)
    const int wave = tid >> 6, lane = tid & 63;
    const int wr = (wave >> 1) * 64, wc = (wave & 1) * 64;
    const int fr = lane & 15, fq = lane >> 4;
    unsigned short* As = (unsigned short*)hlds;          // [128][128]
    unsigned short* Bs = As + 128*128;
    const unsigned short* hsA = (const unsigned short*)(hsx + 16384);
    const int srow0 = wave*32;
    const int lrow = lane >> 4;
    const int lch  = lane & 15;
    int fenced = 0;

    for (int tile = dBlk; tile < 32*250; tile += NDB){
      const int mt = tile/250, nt = tile - mt*250;
      const int req = 4*mt + 4;
      if (req > fenced){ WAITH_S(req, 8); fenced = req; }
      const int m1 = mt*128, n1 = nt*128;

      f32x4 acc[4][4];
      #pragma unroll
      for (int i=0;i<4;i++)
        #pragma unroll
        for (int j=0;j<4;j++) acc[i][j] = (f32x4){0.f,0.f,0.f,0.f};

      for (int k0 = 0; k0 < NINP; k0 += 128){
        __syncthreads();
        #pragma unroll
        for (int j=0;j<8;j++){
          const int r = srow0 + j*4 + lrow;
          const unsigned short* gA = hsA + (size_t)(m1 + r)*NINP + k0 + (lch ^ (r&7))*8;
          __builtin_amdgcn_global_load_lds((const unsigned int*)gA,
              (unsigned int*)(As + (size_t)(srow0 + j*4)*128), 16, 0, 0);
        }
        #pragma unroll
        for (int j=0;j<8;j++){
          const int r = srow0 + j*4 + lrow;
          const unsigned short* gB = enc_bf + (size_t)(n1 + r)*NINP + k0 + (lch ^ (r&7))*8;
          __builtin_amdgcn_global_load_lds((const unsigned int*)gB,
              (unsigned int*)(Bs + (size_t)(srow0 + j*4)*128), 16, 0, 0);
        }
        __syncthreads();

        #pragma unroll
        for (int ks=0; ks<4; ks++){
          bf16x8 af[4], bf[4];
          #pragma unroll
          for (int mi=0; mi<4; mi++){
            const int r = wr + mi*16 + fr;
            af[mi] = *(const bf16x8*)(As + (size_t)r*128 + ((ks*4 + fq) ^ (r&7))*8);
          }
          #pragma unroll
          for (int ni=0; ni<4; ni++){
            const int r = wc + ni*16 + fr;
            bf[ni] = *(const bf16x8*)(Bs + (size_t)r*128 + ((ks*4 + fq) ^ (r&7))*8);
          }
          #pragma unroll
          for (int mi=0; mi<4; mi++)
            #pragma unroll
            for (int ni=0; ni<4; ni++)
              acc[mi][ni] = __builtin_amdgcn_mfma_f32_16x16x32_bf16(af[mi], bf[ni], acc[mi][ni], 0, 0, 0);
        }
      }

      #pragma unroll
      for (int ni=0; ni<4; ni++){
        const int col = n1 + wc + ni*16 + fr;
        const float bv = dbias[col];
        #pragma unroll
        for (int mi=0; mi<4; mi++){
          const int row0 = m1 + wr + mi*16 + fq*4;
          #pragma unroll
          for (int j=0; j<4; j++)
            Cout[(size_t)(row0 + j)*NVOCAB + col] = acc[mi][ni][j] + bv;
        }
      }
    }
  }
}

extern "C" void kernel_launch(void* const* d_in, const int* in_sizes, int n_in,
                              void* d_out, int out_size, void* d_ws, size_t ws_size,
                              hipStream_t stream){
  (void)in_sizes; (void)n_in; (void)out_size;
  const int*   inputs = (const int*)  d_in[0];
  const float* h0     = (const float*)d_in[1];
  const float* c0     = (const float*)d_in[2];
  const float* m0     = (const float*)d_in[3];
  const float* enc    = (const float*)d_in[4];
  const float* dbias  = (const float*)d_in[5];
  const float* w_ih   = (const float*)d_in[6];
  const float* w_hh   = (const float*)d_in[7];
  const float* b_ih   = (const float*)d_in[8];
  const float* b_hh   = (const float*)d_in[9];
  const float* conv_w = (const float*)d_in[10];
  const float* conv_b = (const float*)d_in[11];
  const float* pol_w  = (const float*)d_in[12];
  const float* pol_b  = (const float*)d_in[13];

  float* out = (float*)d_out;
  float* ws  = (float*)d_ws;
  // ws layout (f32 slots): lbase 90112 | hsx 2,113,536 | enc_bf 16,384,000 | flags 1040
  float* lbase = ws;
  unsigned int* hsx = (unsigned int*)(ws + 90112);
  unsigned short* hs_bf  = (unsigned short*)(hsx + 16384);      // slots 1..128 = h(0..127)
  unsigned short* enc_bf = (unsigned short*)(ws + 90112 + 2113536);
  int* flags_ws          = (int*)(ws + 90112 + 2113536 + 16384000);
  const int overlap = (ws_size >= (size_t)18600000*4);
  float* xg = overlap ? (out + XG_OFF) : out;
  unsigned short* w_swz = (unsigned short*)(out + 17000000);    // 4 MB (read once at scan start)
  int* flags = overlap ? flags_ws : (int*)(out + 19600000);
  float* ot = out + DEC_OFF;                                    // hT | cT | memT

  k_init<<<64, 256, 0, stream>>>(h0, hsx);
  k_wconv<<<2048, 256, 0, stream>>>(w_hh, w_swz);

  // xg[m,j] = emb(m).w_ih[j] + b_ih[j] + b_hh[j]   (4096x4096x1024 bf16 MFMA)
  dim3 gxg(32, 32);
  k_gemm_bf16<<<gxg, 256, 0, stream>>>(enc, inputs, w_ih, b_ih, b_hh, xg, NINP, NGATE);

  k_xp<<<SEQ*BATCH, 256, 0, stream>>>(enc, inputs, pol_w, pol_b, conv_b, lbase);

  hipMemsetAsync(flags, 0, (64*16 + 16)*sizeof(int), stream);

  const int nblk = overlap ? (NGB + NMB + NDB) : (NGB + NMB);
  k_scan<<<nblk, 256, 0, stream>>>(xg, w_swz, conv_w, lbase, hsx, c0, m0,
                                   ot, flags, enc_bf, dbias, out, enc);

  if (!overlap){
    dim3 gdec(32, 250);
    k_gemm_dec<<<gdec, 256, 0, stream>>>(hs_bf, enc, dbias, out);
  }
}

// Round 19
// 1180.673 us; speedup vs baseline: 1.9135x; 1.1714x over previous
//
#include <hip/hip_runtime.h>
#include <math.h>

#define SEQ    128
#define BATCH  32
#define NINP   1024
#define NGATE  4096   // 4*NINP
#define DEPTH  10
#define NPOL   22     // 2*(DEPTH+1)
#define NVOCAB 32000
#define DEC_OFF 131072000ll   // SEQ*BATCH*NVOCAB
#define NGB    64             // gate blocks (blk 0-63  -> XCD 0-1 under chunked dispatch)
#define NMB    32             // mem blocks  (blk 64-95 -> XCD 2)
#define NDB    160            // decode blocks (blk 96-255 -> XCD 3-7)
#define XG_OFF 114294784      // DEC_OFF - 16777216: xg in the TAIL of decoded (rows 3572+)

typedef __attribute__((ext_vector_type(8))) short bf16x8;
typedef __attribute__((ext_vector_type(4))) float f32x4;

__device__ __forceinline__ float sigf(float x){ return 1.0f/(1.0f + expf(-x)); }

__device__ __forceinline__ unsigned short f2bf(float x){
  unsigned int u = __float_as_uint(x);
  unsigned int r = (u + 0x7FFFu + ((u >> 16) & 1u)) >> 16;   // RNE
  return (unsigned short)r;
}
__device__ __forceinline__ float bf2f(unsigned short u){
  return __uint_as_float(((unsigned int)u) << 16);
}

// coherent loads (read at the device coherence point; no cache maintenance).
// Correctness of this path proven in R14 (passed with producer-release).
__device__ __forceinline__ bf16x8 load_co_b128(const unsigned int* p){
  bf16x8 v;
  asm volatile("global_load_dwordx4 %0, %1, off sc0 sc1" : "=v"(v) : "v"(p));
  return v;
}
__device__ __forceinline__ unsigned long long load_co_u64(const unsigned int* p){
  unsigned long long v;
  asm volatile("global_load_dwordx2 %0, %1, off sc0 sc1\n\ts_waitcnt vmcnt(0)"
               : "=v"(v) : "v"(p) : "memory");
  return v;
}

// ---------------- init: h0 -> packed bf16 pairs into hsx slot 0 ----------------
__global__ __launch_bounds__(256) void k_init(const float* __restrict__ h0,
    unsigned int* __restrict__ hsx0){
  int i = blockIdx.x*256 + threadIdx.x;   // < 16384
  unsigned int u = (unsigned int)f2bf(h0[2*i]) | ((unsigned int)f2bf(h0[2*i+1]) << 16);
  hsx0[i] = u;                            // layout: b*512 + n/2
}

// ---------------- w_hh -> bf16, swizzled to per-wave MFMA fragment layout ----------------
__global__ __launch_bounds__(256) void k_wconv(const float* __restrict__ w_hh,
    unsigned short* __restrict__ w_swz){
  int id = blockIdx.x*256 + threadIdx.x;          // 0..524287
  int lane = id & 63, kc = (id>>6)&7, kq = (id>>9)&3, nt = id>>11;
  int j = nt*16 + (lane&15);
  int k = kq*256 + kc*32 + (lane>>4)*8;
  const float* src = w_hh + (size_t)j*NINP + k;
  bf16x8 d;
  #pragma unroll
  for (int e=0;e<8;e++) d[e] = (short)f2bf(src[e]);
  *(bf16x8*)(w_swz + (size_t)id*8) = d;
}

// ---------------- bf16 MFMA GEMM (f32 sources, reg-staged): C = A.B^T + bias ----------------
__global__ __launch_bounds__(256) void k_gemm_bf16(
    const float* __restrict__ A, const int* __restrict__ Aidx,
    const float* __restrict__ B, const float* __restrict__ bias0,
    const float* __restrict__ bias1, float* __restrict__ C,
    int K, int ldc){
  __shared__ __align__(16) unsigned short As[128][40];
  __shared__ __align__(16) unsigned short Bs[128][40];
  const int m1 = blockIdx.y*128, n1 = blockIdx.x*128;
  const int tid = threadIdx.x;
  const int wave = tid >> 6, lane = tid & 63;
  const int wr = (wave >> 1) * 64, wc = (wave & 1) * 64;
  const int fr = lane & 15, fq = lane >> 4;

  f32x4 acc[4][4];
  #pragma unroll
  for (int i=0;i<4;i++)
    #pragma unroll
    for (int j=0;j<4;j++) acc[i][j] = (f32x4){0.f,0.f,0.f,0.f};

  const int sr = tid >> 1, sk = (tid & 1) * 16;
  const float* arow = Aidx ? (A + (size_t)Aidx[m1+sr]*K) : (A + (size_t)(m1+sr)*K);
  const float* brow = B + (size_t)(n1+sr)*K;

  for (int k0 = 0; k0 < K; k0 += 32){
    float4 a0 = *(const float4*)(arow + k0 + sk);
    float4 a1 = *(const float4*)(arow + k0 + sk + 4);
    float4 a2 = *(const float4*)(arow + k0 + sk + 8);
    float4 a3 = *(const float4*)(arow + k0 + sk + 12);
    float4 b0 = *(const float4*)(brow + k0 + sk);
    float4 b1 = *(const float4*)(brow + k0 + sk + 4);
    float4 b2 = *(const float4*)(brow + k0 + sk + 8);
    float4 b3 = *(const float4*)(brow + k0 + sk + 12);
    bf16x8 ap0, ap1, bp0, bp1;
    ap0[0]=f2bf(a0.x); ap0[1]=f2bf(a0.y); ap0[2]=f2bf(a0.z); ap0[3]=f2bf(a0.w);
    ap0[4]=f2bf(a1.x); ap0[5]=f2bf(a1.y); ap0[6]=f2bf(a1.z); ap0[7]=f2bf(a1.w);
    ap1[0]=f2bf(a2.x); ap1[1]=f2bf(a2.y); ap1[2]=f2bf(a2.z); ap1[3]=f2bf(a2.w);
    ap1[4]=f2bf(a3.x); ap1[5]=f2bf(a3.y); ap1[6]=f2bf(a3.z); ap1[7]=f2bf(a3.w);
    bp0[0]=f2bf(b0.x); bp0[1]=f2bf(b0.y); bp0[2]=f2bf(b0.z); bp0[3]=f2bf(b0.w);
    bp0[4]=f2bf(b1.x); bp0[5]=f2bf(b1.y); bp0[6]=f2bf(b1.z); bp0[7]=f2bf(b1.w);
    bp1[0]=f2bf(b2.x); bp1[1]=f2bf(b2.y); bp1[2]=f2bf(b2.z); bp1[3]=f2bf(b2.w);
    bp1[4]=f2bf(b3.x); bp1[5]=f2bf(b3.y); bp1[6]=f2bf(b3.z); bp1[7]=f2bf(b3.w);

    __syncthreads();
    *(bf16x8*)&As[sr][sk]     = ap0;
    *(bf16x8*)&As[sr][sk + 8] = ap1;
    *(bf16x8*)&Bs[sr][sk]     = bp0;
    *(bf16x8*)&Bs[sr][sk + 8] = bp1;
    __syncthreads();

    bf16x8 af[4], bf[4];
    #pragma unroll
    for (int mi=0; mi<4; mi++) af[mi] = *(const bf16x8*)&As[wr + mi*16 + fr][fq*8];
    #pragma unroll
    for (int ni=0; ni<4; ni++) bf[ni] = *(const bf16x8*)&Bs[wc + ni*16 + fr][fq*8];
    #pragma unroll
    for (int mi=0; mi<4; mi++)
      #pragma unroll
      for (int ni=0; ni<4; ni++)
        acc[mi][ni] = __builtin_amdgcn_mfma_f32_16x16x32_bf16(af[mi], bf[ni], acc[mi][ni], 0, 0, 0);
  }

  #pragma unroll
  for (int ni=0; ni<4; ni++){
    const int col = n1 + wc + ni*16 + fr;
    const float bv = (bias0 ? bias0[col] : 0.f) + (bias1 ? bias1[col] : 0.f);
    #pragma unroll
    for (int mi=0; mi<4; mi++){
      const int row0 = m1 + wr + mi*16 + fq*4;
      #pragma unroll
      for (int j=0; j<4; j++)
        C[(size_t)(row0 + j)*ldc + col] = acc[mi][ni][j] + bv;
    }
  }
}

// ---------------- decode fallback (A bf16, B f32): only when ws too small ----------------
__global__ __launch_bounds__(256) void k_gemm_dec(
    const unsigned short* __restrict__ A, const float* __restrict__ B,
    const float* __restrict__ bias, float* __restrict__ C){
  __shared__ __align__(16) unsigned short As[128][40];
  __shared__ __align__(16) unsigned short Bs[128][40];
  const int m1 = blockIdx.x*128, n1 = blockIdx.y*128;
  const int tid = threadIdx.x;
  const int wave = tid >> 6, lane = tid & 63;
  const int wr = (wave >> 1) * 64, wc = (wave & 1) * 64;
  const int fr = lane & 15, fq = lane >> 4;

  f32x4 acc[4][4];
  #pragma unroll
  for (int i=0;i<4;i++)
    #pragma unroll
    for (int j=0;j<4;j++) acc[i][j] = (f32x4){0.f,0.f,0.f,0.f};

  const int sr = tid >> 1, sk = (tid & 1) * 16;
  const unsigned short* arow = A + (size_t)(m1+sr)*NINP;
  const float* brow = B + (size_t)(n1+sr)*NINP;

  for (int k0 = 0; k0 < NINP; k0 += 32){
    bf16x8 ap0 = *(const bf16x8*)(arow + k0 + sk);
    bf16x8 ap1 = *(const bf16x8*)(arow + k0 + sk + 8);
    float4 b0 = *(const float4*)(brow + k0 + sk);
    float4 b1 = *(const float4*)(brow + k0 + sk + 4);
    float4 b2 = *(const float4*)(brow + k0 + sk + 8);
    float4 b3 = *(const float4*)(brow + k0 + sk + 12);
    bf16x8 bp0, bp1;
    bp0[0]=f2bf(b0.x); bp0[1]=f2bf(b0.y); bp0[2]=f2bf(b0.z); bp0[3]=f2bf(b0.w);
    bp0[4]=f2bf(b1.x); bp0[5]=f2bf(b1.y); bp0[6]=f2bf(b1.z); bp0[7]=f2bf(b1.w);
    bp1[0]=f2bf(b2.x); bp1[1]=f2bf(b2.y); bp1[2]=f2bf(b2.z); bp1[3]=f2bf(b2.w);
    bp1[4]=f2bf(b3.x); bp1[5]=f2bf(b3.y); bp1[6]=f2bf(b3.z); bp1[7]=f2bf(b3.w);

    __syncthreads();
    *(bf16x8*)&As[sr][sk]     = ap0;
    *(bf16x8*)&As[sr][sk + 8] = ap1;
    *(bf16x8*)&Bs[sr][sk]     = bp0;
    *(bf16x8*)&Bs[sr][sk + 8] = bp1;
    __syncthreads();

    bf16x8 af[4], bf[4];
    #pragma unroll
    for (int mi=0; mi<4; mi++) af[mi] = *(const bf16x8*)&As[wr + mi*16 + fr][fq*8];
    #pragma unroll
    for (int ni=0; ni<4; ni++) bf[ni] = *(const bf16x8*)&Bs[wc + ni*16 + fr][fq*8];
    #pragma unroll
    for (int mi=0; mi<4; mi++)
      #pragma unroll
      for (int ni=0; ni<4; ni++)
        acc[mi][ni] = __builtin_amdgcn_mfma_f32_16x16x32_bf16(af[mi], bf[ni], acc[mi][ni], 0, 0, 0);
  }

  #pragma unroll
  for (int ni=0; ni<4; ni++){
    const int col = n1 + wc + ni*16 + fr;
    const float bv = bias[col];
    #pragma unroll
    for (int mi=0; mi<4; mi++){
      const int row0 = m1 + wr + mi*16 + fq*4;
      #pragma unroll
      for (int j=0; j<4; j++)
        C[(size_t)(row0 + j)*NVOCAB + col] = acc[mi][ni][j] + bv;
    }
  }
}

// ---------------- logit_base[t][b][p] = emb.pol_w[p] + pol_b[p] + conv_b[p/11] ----------------
__global__ __launch_bounds__(256) void k_xp(const float* __restrict__ enc,
    const int* __restrict__ inputs, const float* __restrict__ pol_w,
    const float* __restrict__ pol_b, const float* __restrict__ conv_b,
    float* __restrict__ logit_base){
  const int m = blockIdx.x;
  const float* x = enc + (size_t)inputs[m]*NINP;
  __shared__ float xs[NINP];
  for (int i=threadIdx.x; i<NINP; i+=256) xs[i] = x[i];
  __syncthreads();
  const int wave = threadIdx.x >> 6, lane = threadIdx.x & 63;
  for (int p = wave; p < NPOL; p += 4){
    const float* w = pol_w + (size_t)p*NINP;
    float s = 0.f;
    for (int k=lane; k<NINP; k+=64) s = fmaf(xs[k], w[k], s);
    #pragma unroll
    for (int off=32; off; off>>=1) s += __shfl_down(s, off);
    if (lane==0) logit_base[(size_t)m*NPOL + p] = s + pol_b[p] + conv_b[p/11];
  }
}

// ===== barrier primitives =====
// ARRIVE (producer): h already published via agent-scope ATOMIC stores (data at the
// coherence point); __syncthreads drains vmcnt (stores completed) before the flag store.
// No release fence needed — nothing dirty in L2 to write back.
#define ARRIVE(VAL)                                                                     \
  __syncthreads();                                                                      \
  if (tid == 0)                                                                         \
    __hip_atomic_store(flags + blk*16, (VAL), __ATOMIC_RELAXED, __HIP_MEMORY_SCOPE_AGENT);
// WAITH_NF (gate/mem consumers): poll only, NO acquire fence — h is read with coherent
// sc0sc1 loads (reads the coherence point directly; R14-proven correct).
#define WAITH_NF(VAL)                                                                   \
  if (tid < 64){                                                                        \
    int v_ = __hip_atomic_load(flags + tid*16, __ATOMIC_RELAXED, __HIP_MEMORY_SCOPE_AGENT); \
    while (__ballot(v_ < (VAL)) != 0ull){                                               \
      __builtin_amdgcn_s_sleep(1);                                                      \
      v_ = __hip_atomic_load(flags + tid*16, __ATOMIC_RELAXED, __HIP_MEMORY_SCOPE_AGENT); \
    }                                                                                   \
  }                                                                                     \
  __syncthreads();
// WAITH_F (decode): poll + acquire fence (invalidate) — decode reads hs via plain
// global_load_lds and fences only ~32x per block per launch (decode XCDs only).
#define WAITH_F(VAL, SLP)                                                               \
  if (tid < 64){                                                                        \
    int v_ = __hip_atomic_load(flags + tid*16, __ATOMIC_RELAXED, __HIP_MEMORY_SCOPE_AGENT); \
    while (__ballot(v_ < (VAL)) != 0ull){                                               \
      __builtin_amdgcn_s_sleep(SLP);                                                    \
      v_ = __hip_atomic_load(flags + tid*16, __ATOMIC_RELAXED, __HIP_MEMORY_SCOPE_AGENT); \
    }                                                                                   \
    if (tid == 0) __builtin_amdgcn_fence(__ATOMIC_ACQUIRE, "agent");                    \
  }                                                                                     \
  __syncthreads();

// ---------------- persistent kernel: 64 gate + 32 mem + (overlap) 160 decode blocks ----------------
// LINEAR role mapping (chunked dispatch co-locates consecutive blocks => natural XCD partition).
__global__ __launch_bounds__(256, 1) void k_scan(
    const float* __restrict__ xg, const unsigned short* __restrict__ w_swz,
    const float* __restrict__ conv_w, const float* __restrict__ lbase,
    unsigned int* __restrict__ hsx, const float* __restrict__ c0,
    const float* __restrict__ m0, float* __restrict__ ot, int* __restrict__ flags,
    const unsigned short* __restrict__ enc_bf, const float* __restrict__ dbias,
    float* __restrict__ Cout, const float* __restrict__ enc){
  const int blk = blockIdx.x, tid = threadIdx.x;

  __shared__ __align__(16) unsigned short hlds[32*1024];
  __shared__ float gl[32][68];

  if (blk < NGB){
    // =================== gate block ===================
    const int wv = tid >> 6, lane = tid & 63;
    const int fr = lane & 15, fq = lane >> 4;
    const int n0 = blk * 16;
    bf16x8 wreg[32];
    {
      const unsigned short* wb = w_swz + ((size_t)(wv*64 + blk)*32*64 + (size_t)lane)*8;
      #pragma unroll
      for (int ks=0; ks<32; ks++) wreg[ks] = *(const bf16x8*)(wb + (size_t)ks*512);
    }
    const int eb = tid >> 3, ej0 = (tid & 7)*2, en0 = n0 + ej0;
    float creg0 = c0[eb*NINP + en0], creg1 = c0[eb*NINP + en0 + 1];
    const int sb = tid >> 3, seg = tid & 7;

    for (int t=0; t<SEQ; ++t){
      const float* xr = xg + ((size_t)t*BATCH + eb)*NGATE + en0;
      const float2 x_i = *(const float2*)(xr);
      const float2 x_f = *(const float2*)(xr + NINP);
      const float2 x_g = *(const float2*)(xr + 2*NINP);
      const float2 x_o = *(const float2*)(xr + 3*NINP);

      WAITH_NF(t)         // h(t-1) = slot t published

      // stage h(t-1): coherent sc0sc1 wide loads (16 in flight), then swizzled LDS write
      {
        const unsigned int* hsrc = hsx + (size_t)t*16384 + sb*512;
        bf16x8 tmp[16];
        #pragma unroll
        for (int i=0;i<16;i++)
          tmp[i] = load_co_b128(hsrc + (seg*16 + i)*4);
        asm volatile("s_waitcnt vmcnt(0)" ::: "memory");
        #pragma unroll
        for (int i=0;i<16;i++){
          int ch = seg*16 + i;
          ((bf16x8*)hlds)[sb*128 + (ch ^ (sb&7))] = tmp[i];
        }
      }
      __syncthreads();

      f32x4 acc0 = {0.f,0.f,0.f,0.f}, acc1 = {0.f,0.f,0.f,0.f};
      #pragma unroll
      for (int ks=0; ks<32; ks++){
        bf16x8 a0 = ((const bf16x8*)hlds)[fr*128      + ((ks*4 + fq) ^ (fr&7))];
        bf16x8 a1 = ((const bf16x8*)hlds)[(16+fr)*128 + ((ks*4 + fq) ^ (fr&7))];
        acc0 = __builtin_amdgcn_mfma_f32_16x16x32_bf16(a0, wreg[ks], acc0, 0,0,0);
        acc1 = __builtin_amdgcn_mfma_f32_16x16x32_bf16(a1, wreg[ks], acc1, 0,0,0);
      }
      #pragma unroll
      for (int r=0;r<4;r++){
        gl[fq*4 + r][wv*16 + fr]      = acc0[r];
        gl[16 + fq*4 + r][wv*16 + fr] = acc1[r];
      }
      __syncthreads();

      {
        float gi0 = sigf (gl[eb][ej0]      + x_i.x), gi1 = sigf (gl[eb][ej0+1]      + x_i.y);
        float gf0 = sigf (gl[eb][16+ej0]   + x_f.x), gf1 = sigf (gl[eb][16+ej0+1]   + x_f.y);
        float gg0 = tanhf(gl[eb][32+ej0]   + x_g.x), gg1 = tanhf(gl[eb][32+ej0+1]   + x_g.y);
        float go0 = sigf (gl[eb][48+ej0]   + x_o.x), go1 = sigf (gl[eb][48+ej0+1]   + x_o.y);
        float cc0 = gf0*creg0 + gi0*gg0,  cc1 = gf1*creg1 + gi1*gg1;
        float hh0 = go0*tanhf(cc0),       hh1 = go1*tanhf(cc1);
        creg0 = cc0; creg1 = cc1;
        unsigned int pk = (unsigned int)f2bf(hh0) | ((unsigned int)f2bf(hh1) << 16);
        // publish h(t) directly to the coherence point (agent-scope atomic store)
        __hip_atomic_store(hsx + (size_t)(t+1)*16384 + eb*512 + (en0>>1), pk,
                           __ATOMIC_RELAXED, __HIP_MEMORY_SCOPE_AGENT);
        if (t == SEQ-1){
          ot[eb*NINP + en0] = hh0;  ot[eb*NINP + en0 + 1] = hh1;             // hT
          ot[BATCH*NINP + eb*NINP + en0] = cc0;                              // cT
          ot[BATCH*NINP + eb*NINP + en0 + 1] = cc1;
        }
      }
      ARRIVE(t+1)
    }
  } else if (blk < NGB + NMB) {
    // =================== mem block ===================
    const int b = blk - NGB;
    const int wv = tid >> 6, lane = tid & 63;
    const int col0 = tid*4;
    __shared__ float red[NPOL][4];
    __shared__ float sp[NPOL];
    float m[4][DEPTH];
    #pragma unroll
    for (int c=0;c<4;c++)
      #pragma unroll
      for (int d=0;d<DEPTH;d++) m[c][d] = m0[(size_t)b*DEPTH*NINP + d*NINP + col0 + c];
    float cw0[2][4], cw1[2][4];
    #pragma unroll
    for (int o=0;o<2;o++)
      #pragma unroll
      for (int c=0;c<4;c++){
        cw0[o][c] = conv_w[o*2*NINP + 2*(col0+c)];
        cw1[o][c] = conv_w[o*2*NINP + 2*(col0+c) + 1];
      }

    for (int t=0; t<SEQ; ++t){
      float lp[NPOL];
      #pragma unroll
      for (int o=0;o<2;o++)
        #pragma unroll
        for (int tp=0; tp<11; tp++){
          float v = 0.f;
          #pragma unroll
          for (int c=0;c<4;c++){
            if (tp < DEPTH)   v = fmaf(m[c][tp],   cw0[o][c], v);
            if (tp+1 < DEPTH) v = fmaf(m[c][tp+1], cw1[o][c], v);
          }
          lp[o*11+tp] = v;
        }
      #pragma unroll
      for (int p=0;p<NPOL;p++){
        #pragma unroll
        for (int off=32; off; off>>=1) lp[p] += __shfl_down(lp[p], off);
      }
      if (lane == 0){
        #pragma unroll
        for (int p=0;p<NPOL;p++) red[p][wv] = lp[p];
      }
      __syncthreads();
      if (tid == 0){
        float l[NPOL]; float mx = -1e30f;
        #pragma unroll
        for (int p=0;p<NPOL;p++){
          l[p] = red[p][0]+red[p][1]+red[p][2]+red[p][3]
               + lbase[(size_t)t*(BATCH*NPOL) + b*NPOL + p];
          mx = fmaxf(mx, l[p]);
        }
        float sum = 0.f;
        #pragma unroll
        for (int p=0;p<NPOL;p++){ l[p] = expf(l[p]-mx); sum += l[p]; }
        float inv = 1.f/sum;
        #pragma unroll
        for (int p=0;p<NPOL;p++) sp[p] = l[p]*inv;
      }
      WAITH_NF(t+1)       // h(t) = slot t+1 published (also makes sp visible)

      unsigned long long hv = load_co_u64(hsx + (size_t)(t+1)*16384 + b*512 + (col0>>1));
      float hc[4];
      hc[0] = bf2f((unsigned short)hv);
      hc[1] = bf2f((unsigned short)(hv >> 16));
      hc[2] = bf2f((unsigned short)(hv >> 32));
      hc[3] = bf2f((unsigned short)(hv >> 48));

      float psum = 0.f;
      #pragma unroll
      for (int k2=11;k2<22;k2++) psum += sp[k2];
      #pragma unroll
      for (int c=0;c<4;c++){
        float outv[DEPTH];
        {
          float v = psum*hc[c];
          #pragma unroll
          for (int jj=0;jj<DEPTH;jj++) v = fmaf(sp[jj], m[c][jj], v);
          outv[0] = v;
        }
        #pragma unroll
        for (int d=1; d<DEPTH; d++){
          float v = 0.f;
          for (int jj=d;   jj<DEPTH; jj++) v = fmaf(sp[jj-d],    m[c][jj], v);
          for (int jj=d-1; jj<DEPTH; jj++) v = fmaf(sp[12+jj-d], m[c][jj], v);
          outv[d] = v;
        }
        #pragma unroll
        for (int d=0;d<DEPTH;d++) m[c][d] = outv[d];
      }
      __syncthreads();
      if (t == SEQ-1){
        #pragma unroll
        for (int c=0;c<4;c++)
          #pragma unroll
          for (int d=0;d<DEPTH;d++)
            ot[2*BATCH*NINP + (size_t)b*DEPTH*NINP + d*NINP + col0 + c] = m[c][d];
      }
    }
  } else {
    // =================== decode block: enc->bf16 prologue + BK=128 GEMM ===================
    const int dBlk = blk - (NGB + NMB);
    int* ecnt = flags + 1024;

    // one-time prologue: enc f32 -> bf16 (hides under the scan's first steps)
    {
      unsigned short* ebw = (unsigned short*)enc_bf;
      for (int it = dBlk*256 + tid; it < 2048000; it += NDB*256){
        const float* s = enc + (size_t)it*16;
        float4 a0 = *(const float4*)(s);
        float4 a1 = *(const float4*)(s+4);
        float4 a2 = *(const float4*)(s+8);
        float4 a3 = *(const float4*)(s+12);
        bf16x8 o0, o1;
        o0[0]=f2bf(a0.x); o0[1]=f2bf(a0.y); o0[2]=f2bf(a0.z); o0[3]=f2bf(a0.w);
        o0[4]=f2bf(a1.x); o0[5]=f2bf(a1.y); o0[6]=f2bf(a1.z); o0[7]=f2bf(a1.w);
        o1[0]=f2bf(a2.x); o1[1]=f2bf(a2.y); o1[2]=f2bf(a2.z); o1[3]=f2bf(a2.w);
        o1[4]=f2bf(a3.x); o1[5]=f2bf(a3.y); o1[6]=f2bf(a3.z); o1[7]=f2bf(a3.w);
        *(bf16x8*)(ebw + (size_t)it*16)     = o0;
        *(bf16x8*)(ebw + (size_t)it*16 + 8) = o1;
      }
      __syncthreads();
      if (tid == 0){
        __builtin_amdgcn_fence(__ATOMIC_RELEASE, "agent");
        __hip_atomic_fetch_add(ecnt, 1, __ATOMIC_RELAXED, __HIP_MEMORY_SCOPE_AGENT);
        while (__hip_atomic_load(ecnt, __ATOMIC_RELAXED, __HIP_MEMORY_SCOPE_AGENT) < NDB)
          __builtin_amdgcn_s_sleep(8);
        __builtin_amdgcn_fence(__ATOMIC_ACQUIRE, "agent");
      }
      __syncthreads();
    }

    // BK=128 decode GEMM, gated by scan progress (tile needs hsx slots <= 4mt+4)
    const int wave = tid >> 6, lane = tid & 63;
    const int wr = (wave >> 1) * 64, wc = (wave & 1) * 64;
    const int fr = lane & 15, fq = lane >> 4;
    unsigned short* As = (unsigned short*)hlds;          // [128][128]
    unsigned short* Bs = As + 128*128;
    const unsigned short* hsA = (const unsigned short*)(hsx + 16384);
    const int srow0 = wave*32;
    const int lrow = lane >> 4;
    const int lch  = lane & 15;
    int fenced = 0;

    for (int tile = dBlk; tile < 32*250; tile += NDB){
      const int mt = tile/250, nt = tile - mt*250;
      const int req = 4*mt + 4;
      if (req > fenced){ WAITH_F(req, 8); fenced = req; }
      const int m1 = mt*128, n1 = nt*128;

      f32x4 acc[4][4];
      #pragma unroll
      for (int i=0;i<4;i++)
        #pragma unroll
        for (int j=0;j<4;j++) acc[i][j] = (f32x4){0.f,0.f,0.f,0.f};

      for (int k0 = 0; k0 < NINP; k0 += 128){
        __syncthreads();
        #pragma unroll
        for (int j=0;j<8;j++){
          const int r = srow0 + j*4 + lrow;
          const unsigned short* gA = hsA + (size_t)(m1 + r)*NINP + k0 + (lch ^ (r&7))*8;
          __builtin_amdgcn_global_load_lds((const unsigned int*)gA,
              (unsigned int*)(As + (size_t)(srow0 + j*4)*128), 16, 0, 0);
        }
        #pragma unroll
        for (int j=0;j<8;j++){
          const int r = srow0 + j*4 + lrow;
          const unsigned short* gB = enc_bf + (size_t)(n1 + r)*NINP + k0 + (lch ^ (r&7))*8;
          __builtin_amdgcn_global_load_lds((const unsigned int*)gB,
              (unsigned int*)(Bs + (size_t)(srow0 + j*4)*128), 16, 0, 0);
        }
        __syncthreads();

        #pragma unroll
        for (int ks=0; ks<4; ks++){
          bf16x8 af[4], bf[4];
          #pragma unroll
          for (int mi=0; mi<4; mi++){
            const int r = wr + mi*16 + fr;
            af[mi] = *(const bf16x8*)(As + (size_t)r*128 + ((ks*4 + fq) ^ (r&7))*8);
          }
          #pragma unroll
          for (int ni=0; ni<4; ni++){
            const int r = wc + ni*16 + fr;
            bf[ni] = *(const bf16x8*)(Bs + (size_t)r*128 + ((ks*4 + fq) ^ (r&7))*8);
          }
          #pragma unroll
          for (int mi=0; mi<4; mi++)
            #pragma unroll
            for (int ni=0; ni<4; ni++)
              acc[mi][ni] = __builtin_amdgcn_mfma_f32_16x16x32_bf16(af[mi], bf[ni], acc[mi][ni], 0, 0, 0);
        }
      }

      #pragma unroll
      for (int ni=0; ni<4; ni++){
        const int col = n1 + wc + ni*16 + fr;
        const float bv = dbias[col];
        #pragma unroll
        for (int mi=0; mi<4; mi++){
          const int row0 = m1 + wr + mi*16 + fq*4;
          #pragma unroll
          for (int j=0; j<4; j++)
            Cout[(size_t)(row0 + j)*NVOCAB + col] = acc[mi][ni][j] + bv;
        }
      }
    }
  }
}

extern "C" void kernel_launch(void* const* d_in, const int* in_sizes, int n_in,
                              void* d_out, int out_size, void* d_ws, size_t ws_size,
                              hipStream_t stream){
  (void)in_sizes; (void)n_in; (void)out_size;
  const int*   inputs = (const int*)  d_in[0];
  const float* h0     = (const float*)d_in[1];
  const float* c0     = (const float*)d_in[2];
  const float* m0     = (const float*)d_in[3];
  const float* enc    = (const float*)d_in[4];
  const float* dbias  = (const float*)d_in[5];
  const float* w_ih   = (const float*)d_in[6];
  const float* w_hh   = (const float*)d_in[7];
  const float* b_ih   = (const float*)d_in[8];
  const float* b_hh   = (const float*)d_in[9];
  const float* conv_w = (const float*)d_in[10];
  const float* conv_b = (const float*)d_in[11];
  const float* pol_w  = (const float*)d_in[12];
  const float* pol_b  = (const float*)d_in[13];

  float* out = (float*)d_out;
  float* ws  = (float*)d_ws;
  // ws layout (f32 slots): lbase 90112 | hsx 2,113,536 | enc_bf 16,384,000 | flags 1040
  float* lbase = ws;
  unsigned int* hsx = (unsigned int*)(ws + 90112);
  unsigned short* hs_bf  = (unsigned short*)(hsx + 16384);      // slots 1..128 = h(0..127)
  unsigned short* enc_bf = (unsigned short*)(ws + 90112 + 2113536);
  int* flags_ws          = (int*)(ws + 90112 + 2113536 + 16384000);
  const int overlap = (ws_size >= (size_t)18600000*4);
  float* xg = overlap ? (out + XG_OFF) : out;
  unsigned short* w_swz = (unsigned short*)(out + 17000000);    // 4 MB (read once at scan start)
  int* flags = overlap ? flags_ws : (int*)(out + 19600000);
  float* ot = out + DEC_OFF;                                    // hT | cT | memT

  k_init<<<64, 256, 0, stream>>>(h0, hsx);
  k_wconv<<<2048, 256, 0, stream>>>(w_hh, w_swz);

  // xg[m,j] = emb(m).w_ih[j] + b_ih[j] + b_hh[j]   (4096x4096x1024 bf16 MFMA)
  dim3 gxg(32, 32);
  k_gemm_bf16<<<gxg, 256, 0, stream>>>(enc, inputs, w_ih, b_ih, b_hh, xg, NINP, NGATE);

  k_xp<<<SEQ*BATCH, 256, 0, stream>>>(enc, inputs, pol_w, pol_b, conv_b, lbase);

  hipMemsetAsync(flags, 0, (64*16 + 16)*sizeof(int), stream);

  const int nblk = overlap ? (NGB + NMB + NDB) : (NGB + NMB);
  k_scan<<<nblk, 256, 0, stream>>>(xg, w_swz, conv_w, lbase, hsx, c0, m0,
                                   ot, flags, enc_bf, dbias, out, enc);

  if (!overlap){
    dim3 gdec(32, 250);
    k_gemm_dec<<<gdec, 256, 0, stream>>>(hs_bf, enc, dbias, out);
  }
}